// Round 5
// baseline (464.599 us; speedup 1.0000x reference)
//
#include <hip/hip_runtime.h>
#include <math.h>

#define NTOK 3136           // 16*14*14 tokens
#define MT 12544            // 4 * NTOK
#define KCV 2304            // 3*3*16*16
#define THRESH 1.5f
#define LN_EPS 1e-5f

typedef short short8 __attribute__((ext_vector_type(8)));
typedef float f32x4 __attribute__((ext_vector_type(4)));

// ---------- bf16 helpers (RTNE) ----------
__device__ __forceinline__ unsigned short f2bf(float f) {
    unsigned int u = __float_as_uint(f);
    u += 0x7fffu + ((u >> 16) & 1u);
    return (unsigned short)(u >> 16);
}
__device__ __forceinline__ float bf2f(unsigned short h) {
    return __uint_as_float(((unsigned int)h) << 16);
}
__device__ __forceinline__ void async16(const void* g, void* l) {
    __builtin_amdgcn_global_load_lds((const __attribute__((address_space(1))) void*)g,
                                     (__attribute__((address_space(3))) void*)l, 16, 0, 0);
}

// ---------- wave helpers (wave = 64) ----------
__device__ __forceinline__ float wsum(float v) {
#pragma unroll
    for (int o = 32; o > 0; o >>= 1) v += __shfl_xor(v, o);
    return v;
}
__device__ __forceinline__ float wmax(float v) {
#pragma unroll
    for (int o = 32; o > 0; o >>= 1) v = fmaxf(v, __shfl_xor(v, o));
    return v;
}

// ---------- prep: conv_w -> hi/lo bf16 ; wk,wv,Wvi -> bf16 pool ----------
__global__ __launch_bounds__(256) void prep_k(
    const float* __restrict__ cw, unsigned short* __restrict__ cwh,
    unsigned short* __restrict__ cwl,
    const float* __restrict__ wk, const float* __restrict__ wv,
    const float* __restrict__ inp, unsigned short* __restrict__ pool)
{
    int i = blockIdx.x * 256 + threadIdx.x;
    if (i < 589824) {                      // 256*KCV
        float a = cw[i];
        unsigned short h = f2bf(a);
        cwh[i] = h;
        cwl[i] = f2bf(a - bf2f(h));
        return;
    }
    int j = i - 589824;
    if (j >= 196608) return;
    float v;
    if      (j <  65536) v = wk[j];
    else if (j < 131072) v = wv[j - 65536];
    else                 v = inp[j];       // Wvi = in_proj_w rows 512..767 = elems [131072,196608)
    pool[j] = f2bf(v);
}

// ---------- fold stage 1: T = Wd@Wo (fp32), and u = Wd@bo + bd + q0 ----------
__global__ __launch_bounds__(256) void foldT_k(
    const float* __restrict__ Wd, const float* __restrict__ Wo,
    const float* __restrict__ bo, const float* __restrict__ bd,
    const float* __restrict__ q0, float* __restrict__ T, float* __restrict__ u)
{
    const int t = threadIdx.x;
    if (blockIdx.x < 256) {
        int f = blockIdx.x;
        float acc = 0.f;
        const float* wdr = Wd + f * 256;
#pragma unroll 4
        for (int e = 0; e < 256; ++e) acc += wdr[e] * Wo[e * 256 + t];
        T[f * 256 + t] = acc;
    } else {
        // u[f] = sum_e bo[e]*Wd[f,e] + bd[f] + q0[f] ; wave-per-row wsum
        const int w = t >> 6, lane = t & 63;
        float4 b4 = reinterpret_cast<const float4*>(bo)[lane];
        for (int i = 0; i < 64; ++i) {
            int row = w * 64 + i;
            float4 w4 = reinterpret_cast<const float4*>(Wd + (size_t)row * 256)[lane];
            float pv = wsum(w4.x * b4.x + w4.y * b4.y + w4.z * b4.z + w4.w * b4.w);
            if (lane == 0) u[row] = pv + bd[row] + q0[row];
        }
    }
}

// ---------- fold stage 2: W3 = Wb@T -> bf16 pool slot; bcomb = Wb@u + bb ----------
__global__ __launch_bounds__(256) void foldW_k(
    const float* __restrict__ Wb, const float* __restrict__ T,
    const float* __restrict__ u, const float* __restrict__ bb,
    unsigned short* __restrict__ W3, float* __restrict__ bcomb)
{
    const int t = threadIdx.x;
    if (blockIdx.x < 256) {
        int f = blockIdx.x;
        float acc = 0.f;
        const float* wbr = Wb + f * 256;
#pragma unroll 4
        for (int e = 0; e < 256; ++e) acc += wbr[e] * T[e * 256 + t];
        W3[f * 256 + t] = f2bf(acc);
    } else {
        const int w = t >> 6, lane = t & 63;
        float4 u4 = reinterpret_cast<const float4*>(u)[lane];
        for (int i = 0; i < 64; ++i) {
            int row = w * 64 + i;
            float4 w4 = reinterpret_cast<const float4*>(Wb + (size_t)row * 256)[lane];
            float pv = wsum(w4.x * u4.x + w4.y * u4.y + w4.z * u4.z + w4.w * u4.w);
            if (lane == 0) bcomb[row] = pv + bb[row];
        }
    }
}

// ---------- conv implicit GEMM, software-pipelined (dbuf LDS, 1 barrier/step) ----------
// batch 0 (blockIdx.x<49): hi/lo split, 3 MFMA; batches 1-3: plain bf16, 1 MFMA
__global__ __launch_bounds__(256) void conv_pipe_k(
    const float* __restrict__ video, const unsigned short* __restrict__ cwh,
    const unsigned short* __restrict__ cwl, const float* __restrict__ cb,
    float* __restrict__ outF, unsigned short* __restrict__ outB)
{
    __shared__ __align__(16) unsigned short Ah[2][2048], Al[2][2048];
    __shared__ __align__(16) unsigned short Bh[2][2048], Bl[2][2048];
    const int t    = threadIdx.x;
    const int lane = t & 63;
    const int w    = t >> 6;
    const int m0   = blockIdx.x * 64;
    const int e0   = blockIdx.y * 64;
    const int l15  = lane & 15, lq = lane >> 4;
    const bool isb0 = (blockIdx.x < 49);

    // staging row geometry: lane <-> row m0+lane
    int m = m0 + lane;
    int b = m / NTOK, n = m % NTOK;
    int d = n / 196, hw = n % 196;
    int h = hw / 14, ww = hw % 14;
    const float* vb = video + (size_t)b * 4816896 + (h * 16) * 224 + ww * 16;
    int dbase = 2 * d - 1;
    const unsigned short* bhrow = cwh + (size_t)(e0 + lane) * KCV;
    const unsigned short* blrow = cwl + (size_t)(e0 + lane) * KCV;

    auto loadA = [&](int step, float4& a0, float4& a1) {
        int k0  = step * 32 + w * 8;
        int c   = k0 / 768;
        int rem = k0 - c * 768;
        int kd  = rem >> 8;
        int r2  = rem & 255;
        int id  = dbase + kd;
        a0 = make_float4(0.f, 0.f, 0.f, 0.f); a1 = a0;
        if (id >= 0) {
            const float* p = vb + (size_t)c * 1605632 + id * 50176 + (r2 >> 4) * 224 + (r2 & 15);
            a0 = *(const float4*)p;
            a1 = *(const float4*)(p + 4);
        }
    };
    auto issueB = [&](int step, int buf) {
        int k0 = step * 32 + w * 8;
        async16(bhrow + k0, &Bh[buf][w * 512]);
        if (isb0) async16(blrow + k0, &Bl[buf][w * 512]);
    };
    auto packA = [&](int buf, float4 a0, float4 a1) {
        float av[8] = {a0.x, a0.y, a0.z, a0.w, a1.x, a1.y, a1.z, a1.w};
        unsigned int ph[4];
        unsigned short hi[8];
#pragma unroll
        for (int j = 0; j < 4; ++j) {
            hi[2 * j]     = f2bf(av[2 * j]);
            hi[2 * j + 1] = f2bf(av[2 * j + 1]);
            ph[j] = (unsigned int)hi[2 * j] | ((unsigned int)hi[2 * j + 1] << 16);
        }
        *(uint4*)&Ah[buf][lane * 8 + w * 512] = make_uint4(ph[0], ph[1], ph[2], ph[3]);
        if (isb0) {
            unsigned int pl[4];
#pragma unroll
            for (int j = 0; j < 4; ++j) {
                unsigned short q0 = f2bf(av[2 * j]     - bf2f(hi[2 * j]));
                unsigned short q1 = f2bf(av[2 * j + 1] - bf2f(hi[2 * j + 1]));
                pl[j] = (unsigned int)q0 | ((unsigned int)q1 << 16);
            }
            *(uint4*)&Al[buf][lane * 8 + w * 512] = make_uint4(pl[0], pl[1], pl[2], pl[3]);
        }
    };

    f32x4 acc[4] = {};
    auto doMfma = [&](int buf) {
        short8 fah = *(const short8*)&Ah[buf][(lq * 64 + w * 16 + l15) * 8];
        if (isb0) {
            short8 fal = *(const short8*)&Al[buf][(lq * 64 + w * 16 + l15) * 8];
#pragma unroll
            for (int ct = 0; ct < 4; ++ct) {
                short8 fbh = *(const short8*)&Bh[buf][(lq * 64 + ct * 16 + l15) * 8];
                short8 fbl = *(const short8*)&Bl[buf][(lq * 64 + ct * 16 + l15) * 8];
                acc[ct] = __builtin_amdgcn_mfma_f32_16x16x32_bf16(fah, fbh, acc[ct], 0, 0, 0);
                acc[ct] = __builtin_amdgcn_mfma_f32_16x16x32_bf16(fah, fbl, acc[ct], 0, 0, 0);
                acc[ct] = __builtin_amdgcn_mfma_f32_16x16x32_bf16(fal, fbh, acc[ct], 0, 0, 0);
            }
        } else {
#pragma unroll
            for (int ct = 0; ct < 4; ++ct) {
                short8 fbh = *(const short8*)&Bh[buf][(lq * 64 + ct * 16 + l15) * 8];
                acc[ct] = __builtin_amdgcn_mfma_f32_16x16x32_bf16(fah, fbh, acc[ct], 0, 0, 0);
            }
        }
    };

    // prologue: stage step 0 into buf 0
    float4 a0c, a1c;
    loadA(0, a0c, a1c);
    issueB(0, 0);
    packA(0, a0c, a1c);
    __syncthreads();
    // pipelined steps 0..70: prefetch step+1 before MFMA(step)
    for (int step = 0; step < 71; ++step) {
        int cur = step & 1, nxt = cur ^ 1;
        float4 a0n, a1n;
        loadA(step + 1, a0n, a1n);       // global->reg, latency overlaps MFMA below
        issueB(step + 1, nxt);           // global->LDS async, drained at barrier below
        doMfma(cur);
        packA(nxt, a0n, a1n);
        __syncthreads();
    }
    doMfma(1);                           // step 71 (staged in buf 1)

    int rbase = m0 + w * 16 + lq * 4;
#pragma unroll
    for (int ct = 0; ct < 4; ++ct) {
        int e = e0 + ct * 16 + l15;
        float bias = cb[e];
#pragma unroll
        for (int r = 0; r < 4; ++r) {
            float v = fmaxf(acc[ct][r] + bias, 0.f);
            size_t off = (size_t)(rbase + r) * 256 + e;
            if (isb0) outF[off] = v;
            outB[off] = f2bf(v);
        }
    }
}

// ---------- K & V projections in one dispatch: grid (196, 8) ----------
__global__ __launch_bounds__(256) void gemm_kv_k(
    const unsigned short* __restrict__ A, const unsigned short* __restrict__ Wk,
    const unsigned short* __restrict__ Wv, const float* __restrict__ bk,
    const float* __restrict__ bv, unsigned short* __restrict__ outK,
    unsigned short* __restrict__ outV)
{
    __shared__ __align__(16) unsigned short As[16384], Bs[16384];
    const int t = threadIdx.x, lane = t & 63, w = t >> 6;
    const int which = blockIdx.y >> 2;
    const int m0 = blockIdx.x * 64, e0 = (blockIdx.y & 3) * 64;
    const int l15 = lane & 15, lq = lane >> 4;
    const unsigned short* W = which ? Wv : Wk;
    const float* bias = which ? bv : bk;
    unsigned short* outB = which ? outV : outK;
    const unsigned short* ga = A + (size_t)(m0 + lane) * 256;
    const unsigned short* gb = W + (size_t)(e0 + lane) * 256;
#pragma unroll
    for (int kg = w; kg < 32; kg += 4) {
        async16(ga + kg * 8, &As[kg * 512]);
        async16(gb + kg * 8, &Bs[kg * 512]);
    }
    f32x4 acc[4] = {};
    __syncthreads();
#pragma unroll
    for (int s = 0; s < 8; ++s) {
        int kg = s * 4 + lq;
        short8 a = *(const short8*)&As[(kg * 64 + w * 16 + l15) * 8];
#pragma unroll
        for (int ct = 0; ct < 4; ++ct) {
            short8 bb = *(const short8*)&Bs[(kg * 64 + ct * 16 + l15) * 8];
            acc[ct] = __builtin_amdgcn_mfma_f32_16x16x32_bf16(a, bb, acc[ct], 0, 0, 0);
        }
    }
    int rbase = m0 + w * 16 + lq * 4;
#pragma unroll
    for (int ct = 0; ct < 4; ++ct) {
        int e = e0 + ct * 16 + l15;
        float bv2 = bias[e];
#pragma unroll
        for (int r = 0; r < 4; ++r)
            outB[(size_t)(rbase + r) * 256 + e] = f2bf(acc[ct][r] + bv2);
    }
}

// ---------- generic bf16 MFMA GEMM (lean) ----------
__global__ __launch_bounds__(256) void gemm_mfma_k(
    const unsigned short* __restrict__ A, const unsigned short* __restrict__ W,
    const float* __restrict__ bias, const int* __restrict__ Sptr,
    float* __restrict__ outF, unsigned short* __restrict__ outB)
{
    __shared__ __align__(16) unsigned short As[16384], Bs[16384];
    const int t = threadIdx.x, lane = t & 63, w = t >> 6;
    const int m0 = blockIdx.x * 64, e0 = blockIdx.y * 64;
    const int l15 = lane & 15, lq = lane >> 4;
    const unsigned short* ga = A + (size_t)(m0 + lane) * 256;
    const unsigned short* gb = W + (size_t)(e0 + lane) * 256;
#pragma unroll
    for (int kg = w; kg < 32; kg += 4) {
        async16(ga + kg * 8, &As[kg * 512]);
        async16(gb + kg * 8, &Bs[kg * 512]);
    }
    f32x4 acc[4] = {};
    __syncthreads();
#pragma unroll
    for (int s = 0; s < 8; ++s) {
        int kg = s * 4 + lq;
        short8 a = *(const short8*)&As[(kg * 64 + w * 16 + l15) * 8];
#pragma unroll
        for (int ct = 0; ct < 4; ++ct) {
            short8 bb = *(const short8*)&Bs[(kg * 64 + ct * 16 + l15) * 8];
            acc[ct] = __builtin_amdgcn_mfma_f32_16x16x32_bf16(a, bb, acc[ct], 0, 0, 0);
        }
    }
    int S = Sptr ? *Sptr : 0x7fffffff;
    int rbase = m0 + w * 16 + lq * 4;
#pragma unroll
    for (int ct = 0; ct < 4; ++ct) {
        int e = e0 + ct * 16 + l15;
        float bv = bias[e];
#pragma unroll
        for (int r = 0; r < 4; ++r) {
            int mm = rbase + r;
            float v = acc[ct][r] + bv;
            if ((mm % NTOK) >= S) v = 0.f;
            size_t off = (size_t)mm * 256 + e;
            if (outF) outF[off] = v;
            if (outB) outB[off] = f2bf(v);
        }
    }
}

// ---------- boundary (784 blocks) + query stage 1 (4 blocks) ----------
__global__ __launch_bounds__(256) void bq_k(
    const float* __restrict__ tokens, const float* __restrict__ ent_table,
    int* __restrict__ boundary,
    const float* __restrict__ gq, const float* __restrict__ wq_w,
    const float* __restrict__ wq_b, float* __restrict__ qpre)
{
    const int t = threadIdx.x, lane = t & 63, w = t >> 6;
    if (blockIdx.x < 784) {
        int n = blockIdx.x * 4 + w;
        const float4 x = reinterpret_cast<const float4*>(tokens + (size_t)n * 256)[lane];
        float mean = wsum(x.x + x.y + x.z + x.w) * (1.f / 256.f);
        float bf = rintf(mean * 255.f);
        bf = fminf(fmaxf(bf, 0.f), 255.f);
        int byte = (int)bf;
        const float4 lg = reinterpret_cast<const float4*>(ent_table + byte * 256)[lane];
        float mx = wmax(fmaxf(fmaxf(lg.x, lg.y), fmaxf(lg.z, lg.w)));
        float e0 = expf(lg.x - mx), e1 = expf(lg.y - mx), e2 = expf(lg.z - mx), e3 = expf(lg.w - mx);
        float z = wsum(e0 + e1 + e2 + e3);
        float iz = 1.f / z;
        float p0 = e0 * iz, p1 = e1 * iz, p2 = e2 * iz, p3 = e3 * iz;
        float ep = -(p0 * log2f(p0 + 1e-9f) + p1 * log2f(p1 + 1e-9f) +
                     p2 * log2f(p2 + 1e-9f) + p3 * log2f(p3 + 1e-9f));
        ep = wsum(ep);
        if (lane == 0) boundary[n] = (ep > THRESH) ? 1 : 0;
    } else {
        int q = blockIdx.x - 784;                 // 0..3 -> rows q*64 .. q*64+63
        float4 g4 = reinterpret_cast<const float4*>(gq)[lane];
        for (int i = 0; i < 16; ++i) {
            int row = q * 64 + w * 16 + i;
            float4 wr = reinterpret_cast<const float4*>(wq_w + (size_t)row * 256)[lane];
            float pv = wsum(g4.x * wr.x + g4.y * wr.y + g4.z * wr.z + g4.w * wr.w);
            if (lane == 0) qpre[row] = pv + wq_b[row];
        }
    }
}

// ---------- scan (block 0) + query stage 2: LN, qp, U, c (block 1) ----------
__global__ __launch_bounds__(256) void sq2_k(
    const int* __restrict__ boundary, int* __restrict__ seg_start, int* __restrict__ Sptr,
    const float* __restrict__ qpre, const float* __restrict__ lnq_g,
    const float* __restrict__ lnq_b, const float* __restrict__ inW,
    const float* __restrict__ inB, float* __restrict__ U, float* __restrict__ cvec)
{
    const int t = threadIdx.x;
    if (blockIdx.x == 0) {
        __shared__ int sums[256];
        const int CH = 13;
        int base = t * CH;
        int s = 0;
        for (int i = 0; i < CH; i++) { int n = base + i; if (n < NTOK) s += boundary[n]; }
        sums[t] = s; __syncthreads();
        for (int o = 1; o < 256; o <<= 1) {
            int v = sums[t];
            int u = (t >= o) ? sums[t - o] : 0;
            __syncthreads();
            sums[t] = v + u;
            __syncthreads();
        }
        int run = (t == 0) ? 0 : sums[t - 1];
        if (t == 0) seg_start[0] = 0;
        for (int i = 0; i < CH; i++) {
            int n = base + i;
            if (n >= NTOK) break;
            int v = boundary[n];
            if (n == NTOK - 1) { Sptr[0] = run + 1; seg_start[run + 1] = NTOK; }
            if (v && (n + 1 < NTOK)) seg_start[run + 1] = n + 1;
            run += v;
        }
    } else {
        __shared__ __align__(16) float sh[256], qpL[256];
        __shared__ float red[256];
        const int w = t >> 6, lane = t & 63;
        float acc = qpre[t];
        red[t] = acc; __syncthreads();
        for (int o = 128; o > 0; o >>= 1) { if (t < o) red[t] += red[t + o]; __syncthreads(); }
        float m = red[0] * (1.f / 256.f);
        __syncthreads();
        float dd = acc - m;
        red[t] = dd * dd; __syncthreads();
        for (int o = 128; o > 0; o >>= 1) { if (t < o) red[t] += red[t + o]; __syncthreads(); }
        float inv = 1.f / sqrtf(red[0] * (1.f / 256.f) + LN_EPS);
        __syncthreads();
        sh[t] = dd * inv * lnq_g[t] + lnq_b[t];
        __syncthreads();
        // qp[row] = (sh @ Wqi[row]) + bqi[row], scaled by dh^-0.5
        float4 s4 = reinterpret_cast<const float4*>(sh)[lane];
        for (int i = 0; i < 64; ++i) {
            int row = w * 64 + i;
            float4 wr = reinterpret_cast<const float4*>(inW + (size_t)row * 256)[lane];
            float pv = wsum(s4.x * wr.x + s4.y * wr.y + s4.z * wr.z + s4.w * wr.w);
            if (lane == 0) qpL[row] = (pv + inB[row]) * 0.125f;
        }
        __syncthreads();
        // U[h][j] = sum_e qp[h*64+e] * Wki[h*64+e, j];  Wki = inW+65536, bki = inB+256
        const float* Wki = inW + 65536;
        const float* bki = inB + 256;
#pragma unroll
        for (int h = 0; h < 4; ++h) {
            float a2 = 0.f;
            for (int e = 0; e < 64; ++e)
                a2 += qpL[h * 64 + e] * Wki[(size_t)(h * 64 + e) * 256 + t];
            U[h * 256 + t] = a2;
        }
        float cv = wsum(qpL[t] * bki[t]);   // wave w covers t in [w*64,(w+1)*64) = head w
        if (lane == 0) cvec[w] = cv;
    }
}

// ---------- row LayerNorm in-place on bf16, two buffers in one dispatch ----------
__global__ __launch_bounds__(256) void ln2_k(
    unsigned short* __restrict__ K, unsigned short* __restrict__ V,
    const float* __restrict__ gk, const float* __restrict__ bk,
    const float* __restrict__ gv, const float* __restrict__ bv)
{
    int row  = blockIdx.x * 4 + (threadIdx.x >> 6);
    int lane = threadIdx.x & 63;
    unsigned short* X = blockIdx.y ? V : K;
    const float* g = blockIdx.y ? gv : gk;
    const float* b = blockIdx.y ? bv : bk;
    ushort4 x4 = reinterpret_cast<ushort4*>(X + (size_t)row * 256)[lane];
    float x0 = bf2f(x4.x), x1 = bf2f(x4.y), x2 = bf2f(x4.z), x3 = bf2f(x4.w);
    float m = wsum(x0 + x1 + x2 + x3) * (1.f / 256.f);
    float d0 = x0 - m, d1 = x1 - m, d2 = x2 - m, d3 = x3 - m;
    float var = wsum(d0 * d0 + d1 * d1 + d2 * d2 + d3 * d3) * (1.f / 256.f);
    float inv = 1.f / sqrtf(var + LN_EPS);
    float4 g4 = reinterpret_cast<const float4*>(g)[lane];
    float4 b4 = reinterpret_cast<const float4*>(b)[lane];
    ushort4 y;
    y.x = f2bf(d0 * inv * g4.x + b4.x);
    y.y = f2bf(d1 * inv * g4.y + b4.y);
    y.z = f2bf(d2 * inv * g4.z + b4.z);
    y.w = f2bf(d3 * inv * g4.w + b4.w);
    reinterpret_cast<ushort4*>(X + (size_t)row * 256)[lane] = y;
}

// ---------- scores = kln @ U + c ; one wave per (b,n) ----------
__global__ __launch_bounds__(256) void sc_k(
    const unsigned short* __restrict__ kln, const float* __restrict__ U,
    const float* __restrict__ cvec, float* __restrict__ sc)
{
    int idx  = blockIdx.x * 4 + (threadIdx.x >> 6);
    int lane = threadIdx.x & 63;
    ushort4 k4 = reinterpret_cast<const ushort4*>(kln + (size_t)idx * 256)[lane];
    float x0 = bf2f(k4.x), x1 = bf2f(k4.y), x2 = bf2f(k4.z), x3 = bf2f(k4.w);
    int b = idx / NTOK, n = idx % NTOK;
#pragma unroll
    for (int h = 0; h < 4; ++h) {
        float4 u4 = reinterpret_cast<const float4*>(U + h * 256)[lane];
        float p = wsum(x0 * u4.x + x1 * u4.y + x2 * u4.z + x3 * u4.w);
        if (lane == 0) sc[(b * 4 + h) * NTOK + n] = p + cvec[h];
    }
}

// ---------- segment softmax-attention; grid (NTOK, NH); wave = batch ----------
__global__ __launch_bounds__(256) void attn_bf_k(const float* __restrict__ sc,
    const unsigned short* __restrict__ vp, const int* __restrict__ seg_start,
    const int* __restrict__ Sptr, unsigned short* __restrict__ attn)
{
    int s    = blockIdx.x;
    int h    = blockIdx.y;
    int b    = threadIdx.x >> 6;
    int lane = threadIdx.x & 63;
    unsigned short* orow = attn + ((size_t)b * NTOK + s) * 256 + h * 64;
    int S = *Sptr;
    if (s >= S) { orow[lane] = 0; return; }
    int st = seg_start[s], en = seg_start[s + 1];
    const float* scr = sc + (b * 4 + h) * NTOK;
    float m = -1e30f;
    for (int n = st; n < en; n++) m = fmaxf(m, scr[n]);
    float den = 0.f, acc = 0.f;
    for (int n = st; n < en; n++) {
        float wgt = expf(scr[n] - m);
        den += wgt;
        acc += wgt * bf2f(vp[((size_t)b * NTOK + n) * 256 + h * 64 + lane]);
    }
    orow[lane] = f2bf(acc / den);
}

extern "C" void kernel_launch(void* const* d_in, const int* in_sizes, int n_in,
                              void* d_out, int out_size, void* d_ws, size_t ws_size,
                              hipStream_t stream)
{
    const float* video      = (const float*)d_in[0];
    const float* conv_w     = (const float*)d_in[1];
    const float* conv_b     = (const float*)d_in[2];
    const float* wq_w       = (const float*)d_in[3];
    const float* wq_b       = (const float*)d_in[4];
    const float* wk_w       = (const float*)d_in[5];
    const float* wk_b       = (const float*)d_in[6];
    const float* wv_w       = (const float*)d_in[7];
    const float* wv_b       = (const float*)d_in[8];
    const float* lnq_g      = (const float*)d_in[9];
    const float* lnq_b      = (const float*)d_in[10];
    const float* lnk_g      = (const float*)d_in[11];
    const float* lnk_b      = (const float*)d_in[12];
    const float* lnv_g      = (const float*)d_in[13];
    const float* lnv_b      = (const float*)d_in[14];
    const float* in_proj_w  = (const float*)d_in[15];
    const float* in_proj_b  = (const float*)d_in[16];
    const float* out_proj_w = (const float*)d_in[17];
    const float* out_proj_b = (const float*)d_in[18];
    const float* dense_w    = (const float*)d_in[19];
    const float* dense_b    = (const float*)d_in[20];
    const float* bproj_w    = (const float*)d_in[21];
    const float* bproj_b    = (const float*)d_in[22];
    const float* group_q    = (const float*)d_in[23];
    const float* ent_table  = (const float*)d_in[24];
    float* out = (float*)d_out;

    // ---- workspace layout (~42 MB) ----
    float* W1f = (float*)d_ws;                                   // MT*256 fp32 (batch0 byte path)
    unsigned short* B1 = (unsigned short*)(W1f + (size_t)MT * 256); // tokens bf16 / attn
    unsigned short* B2 = B1 + (size_t)MT * 256;                  // preK -> kln
    unsigned short* B3 = B2 + (size_t)MT * 256;                  // preV -> vln
    unsigned short* B4 = B3 + (size_t)MT * 256;                  // vp
    unsigned short* cwh = B4 + (size_t)MT * 256;                 // 589824
    unsigned short* cwl = cwh + 589824;
    unsigned short* pool = cwl + 589824;                         // wk|wv|Wvi|W3 (4*65536)
    float* Tm    = (float*)(pool + 262144);                      // 65536 fp32
    float* uvec  = Tm + 65536;                                   // 256
    float* bcomb = uvec + 256;                                   // 256
    float* qpre  = bcomb + 256;                                  // 256
    float* U     = qpre + 256;                                   // 1024
    float* cvec  = U + 1024;                                     // 8 (pad)
    float* sc    = cvec + 8;                                     // 16*NTOK
    int* boundary  = (int*)(sc + 16 * NTOK);
    int* seg_start = boundary + NTOK;
    int* Sp        = seg_start + (NTOK + 1);

    const unsigned short* wkb = pool;
    const unsigned short* wvb = pool + 65536;
    const unsigned short* wvi = pool + 131072;
    unsigned short*       w3b = pool + 196608;

    dim3 blk(256);
    prep_k<<<dim3(3072), blk, 0, stream>>>(conv_w, cwh, cwl, wk_w, wv_w, in_proj_w, pool);
    foldT_k<<<dim3(257), blk, 0, stream>>>(dense_w, out_proj_w, out_proj_b, dense_b,
                                           group_q, Tm, uvec);
    foldW_k<<<dim3(257), blk, 0, stream>>>(bproj_w, Tm, uvec, bproj_b, w3b, bcomb);
    conv_pipe_k<<<dim3(196, 4), blk, 0, stream>>>(video, cwh, cwl, conv_b, W1f, B1);
    bq_k<<<dim3(788), blk, 0, stream>>>(W1f, ent_table, boundary, group_q, wq_w, wq_b, qpre);
    sq2_k<<<dim3(2), blk, 0, stream>>>(boundary, seg_start, Sp, qpre, lnq_g, lnq_b,
                                       in_proj_w, in_proj_b, U, cvec);
    gemm_kv_k<<<dim3(196, 8), blk, 0, stream>>>(B1, wkb, wvb, wk_b, wv_b, B2, B3);
    ln2_k<<<dim3(MT / 4, 2), blk, 0, stream>>>(B2, B3, lnk_g, lnk_b, lnv_g, lnv_b);
    sc_k<<<dim3(MT / 4), blk, 0, stream>>>(B2, U, cvec, sc);
    gemm_mfma_k<<<dim3(196, 4), blk, 0, stream>>>(B3, wvi, in_proj_b + 512,
                                                  nullptr, nullptr, B4);      // vp
    attn_bf_k<<<dim3(NTOK, 4), blk, 0, stream>>>(sc, B4, seg_start, Sp, B1);
    gemm_mfma_k<<<dim3(196, 4), blk, 0, stream>>>(B1, w3b, bcomb, Sp, out, nullptr);
}